// Round 4
// baseline (270.432 us; speedup 1.0000x reference)
//
#include <hip/hip_runtime.h>

#define NB 32
#define NC 511      // T-1 context positions
#define NK 8        // senses (center)
#define NS 8        // senses (context)
#define ND 300      // embedding dim
#define ND4 75      // float4 per row
#define NCG 32      // c-groups per b (16 c's per block)
#define GPB 4       // sub-groups of 4 c's per block
#define EPS_COS 1e-8f

// Math notes (verified R1-R6, absmax 0.0):
//  - positional log-weight is constant => center_pos/query_token_ids unused.
//  - cosine(cen,m) scale-invariant => accumulate unnormalized m~ = sum_c e^a v.
//  - R10 post-mortem: timed window = ~184us fixed ws-poison fills + kernels.
//  - R11 post-mortem: fused k_vam = 3.1 TB/s only. Cause: 512 blocks = 2/CU
//    (8 waves/CU) AND __syncthreads' vmcnt(0) drain serializes each group's
//    HBM loads behind the previous group's compute.
//  - R12: (a) NCG 16->32: 1024 blocks = 4/CU; (b) prefetch next group's NT
//    loads into registers BEFORE phase 2, and use raw s_barrier with
//    lgkmcnt(0)-only drain so the prefetch stays in flight across both
//    barriers (consumed at next group's mean). LDS hazards: barrier1 needs
//    ds_writes drained (lgkmcnt covers); barrier2's ds_reads complete at use.

typedef float nfloat4 __attribute__((ext_vector_type(4)));

__device__ __forceinline__ void n4add(nfloat4& a, const nfloat4& b) { a += b; }

#define ISSUE_LOADS(cptr)                                                     \
    do {                                                                      \
        _Pragma("unroll")                                                     \
        for (int s = 0; s < NS; ++s)                                          \
            X[s] = __builtin_nontemporal_load(&(cptr)[s * ND4 + i0]);         \
        if (has1) {                                                           \
            _Pragma("unroll")                                                 \
            for (int s = 0; s < NS; ++s)                                      \
                Y[s] = __builtin_nontemporal_load(&(cptr)[s * ND4 + i1]);     \
        }                                                                     \
    } while (0)

// ---------------------------------------------------------------------------
// K1: block = (b, cg) owns 16 consecutive c's as 4 groups of 4 (wave w ->
// c = base+w). Per group: (prefetched) NT loads -> tree mean -> v tile in LDS;
// 8 dots vs cen; distributed butterfly; ea -> LDS; raw barrier (lgkm only);
// per-d scalar m~ accumulation; raw barrier. Next group's loads are issued
// before phase 2 and remain in flight across both barriers.
// ---------------------------------------------------------------------------
__global__ __launch_bounds__(256, 4) void k_vam(const float* __restrict__ ctx,
                                                const float* __restrict__ cen,
                                                float* __restrict__ part) {
    const int b    = blockIdx.x >> 5;        // 32 cgroups per b
    const int cg   = blockIdx.x & 31;
    const int w    = threadIdx.x >> 6;       // 4 waves
    const int lane = threadIdx.x & 63;
    const int t    = threadIdx.x;
    const int i0 = lane;
    const int i1 = lane + 64;
    const bool has1  = (i1 < ND4);           // lanes 0..10 own a second float4
    const bool hasd1 = (t < ND - 256);       // threads 0..43 own d = 256+t

    __shared__ float vl[4][ND4 * 4 + 4];     // v tile, padded rows
    __shared__ float al[4][NK];              // ea tile

    const nfloat4* cen4 = (const nfloat4*)cen + (size_t)b * NK * ND4;

    float acc0[NK] = {};                     // m~ partial at d = t
    float acc1[NK] = {};                     // m~ partial at d = 256+t (t<44)

    const int cbase0 = cg * (GPB * 4);
    int  c  = cbase0 + w;
    bool cv = (c < NC);                      // wave-uniform

    nfloat4 X[NS];
    nfloat4 Y[NS] = {};                      // lanes >= 11 stay zero forever

    if (cv) {
        const nfloat4* p = (const nfloat4*)ctx + (size_t)(b * NC + c) * NS * ND4;
        ISSUE_LOADS(p);
    }

    for (int g = 0; g < GPB; ++g) {
        const int cbase = cbase0 + g * 4;
        const int cn = min(4, NC - cbase);   // 3 only for (cg=31, g=3)

        nfloat4 s0 = {}, s1 = {};
        if (cv) {
            // ---- tree mean over senses (consumes X/Y) ----
            n4add(X[0], X[1]); n4add(X[2], X[3]); n4add(X[4], X[5]); n4add(X[6], X[7]);
            n4add(X[0], X[2]); n4add(X[4], X[6]);
            n4add(X[0], X[4]);
            n4add(Y[0], Y[1]); n4add(Y[2], Y[3]); n4add(Y[4], Y[5]); n4add(Y[6], Y[7]);
            n4add(Y[0], Y[2]); n4add(Y[4], Y[6]);
            n4add(Y[0], Y[4]);
            const float inv = 0.125f;        // 1/S
            s0 = X[0] * inv;
            s1 = Y[0] * inv;                 // zero beyond lane 10
        }

        // ---- prefetch next group's ctx rows (in flight across barriers) ----
        const bool cv_next = (g + 1 < GPB) && (cbase0 + (g + 1) * 4 + w < NC);
        if (cv_next) {
            const int cnx = cbase0 + (g + 1) * 4 + w;
            const nfloat4* p =
                (const nfloat4*)ctx + (size_t)(b * NC + cnx) * NS * ND4;
            ISSUE_LOADS(p);
        }

        if (cv) {
            // ---- v -> LDS tile ----
            ((nfloat4*)vl[w])[i0] = s0;
            if (has1) ((nfloat4*)vl[w])[i1] = s1;

            // ---- 8 dots vs cen (L1-resident) ----
            float pk[NK];
#pragma unroll
            for (int k = 0; k < NK; ++k) {
                nfloat4 ca = cen4[k * ND4 + i0];
                float p = ca.x * s0.x + ca.y * s0.y + ca.z * s0.z + ca.w * s0.w;
                if (has1) {
                    nfloat4 cb = cen4[k * ND4 + i1];
                    p += cb.x * s1.x + cb.y * s1.y + cb.z * s1.z + cb.w * s1.w;
                }
                pk[k] = p;
            }

            // ---- distributed exchange-butterfly: lane l -> total for k=l&7 ----
            const bool b0 = (lane & 1) != 0;
            float r[4];
#pragma unroll
            for (int j = 0; j < 4; ++j) {
                float keep = b0 ? pk[2 * j + 1] : pk[2 * j];
                float send = b0 ? pk[2 * j]     : pk[2 * j + 1];
                r[j] = keep + __shfl_xor(send, 1);
            }
            const bool b1 = (lane & 2) != 0;
            float q0, q1;
            { float keep = b1 ? r[1] : r[0]; float send = b1 ? r[0] : r[1];
              q0 = keep + __shfl_xor(send, 2); }
            { float keep = b1 ? r[3] : r[2]; float send = b1 ? r[2] : r[3];
              q1 = keep + __shfl_xor(send, 2); }
            const bool b2 = (lane & 4) != 0;
            float u;
            { float keep = b2 ? q1 : q0; float send = b2 ? q0 : q1;
              u = keep + __shfl_xor(send, 4); }
            u += __shfl_xor(u, 8);
            u += __shfl_xor(u, 16);
            u += __shfl_xor(u, 32);

            if (lane < NK) {
                const float scale = 0.057735026919f; // 1/sqrt(300)
                al[w][lane] = __expf(u * scale);
            }
        }

        // ---- barrier 1: only LDS writes must drain; prefetch stays in flight
        asm volatile("s_waitcnt lgkmcnt(0)" ::: "memory");
        __builtin_amdgcn_s_barrier();

        // ---- phase 2: per-d scalar m~ accumulation (c ascending) ----
        for (int cc = 0; cc < cn; ++cc) {
            float vv0 = vl[cc][t];
#pragma unroll
            for (int k = 0; k < NK; ++k) acc0[k] += al[cc][k] * vv0;
        }
        if (hasd1) {
            for (int cc = 0; cc < cn; ++cc) {
                float vv1 = vl[cc][256 + t];
#pragma unroll
                for (int k = 0; k < NK; ++k) acc1[k] += al[cc][k] * vv1;
            }
        }

        // ---- barrier 2: LDS reads completed at use; pin order, no drains ----
        asm volatile("" ::: "memory");
        __builtin_amdgcn_s_barrier();

        cv = cv_next;
        c += 4;
    }

    // ---- one coalesced part write per k ----
#pragma unroll
    for (int k = 0; k < NK; ++k) {
        float* pp = part + (((size_t)(b * NK + k)) * NCG + cg) * ND;
        pp[t] = acc0[k];
        if (hasd1) pp[256 + t] = acc1[k];
    }
}

// ---------------------------------------------------------------------------
// K2: per b — wave w owns k=w: sum the 32 m~ chunk-partials along d (contiguous
// [NCG][ND] panel per (b,k)), cosine vs cen row, then softmax/argmax/pooled.
// ---------------------------------------------------------------------------
__global__ __launch_bounds__(512) void k_fin2(const float* __restrict__ part,
                                              const float* __restrict__ cen,
                                              float* __restrict__ out) {
    const int b    = blockIdx.x;
    const int w    = threadIdx.x >> 6;       // = k
    const int lane = threadIdx.x & 63;
    __shared__ float sred[NK];
    __shared__ int bidx;

    const float* pp = part + ((size_t)b * NK + w) * NCG * ND;
    const float* cp = cen + (size_t)(b * NK + w) * ND;
    float num = 0.f, n1 = 0.f, n2 = 0.f;
    for (int d = lane; d < ND; d += 64) {
        float mval = 0.f;
#pragma unroll
        for (int cg = 0; cg < NCG; ++cg) mval += pp[cg * ND + d];
        float cv = cp[d];
        num += cv * mval; n1 += cv * cv; n2 += mval * mval;
    }
#pragma unroll
    for (int off = 32; off; off >>= 1) {
        num += __shfl_down(num, off);
        n1  += __shfl_down(n1, off);
        n2  += __shfl_down(n2, off);
    }
    if (lane == 0) {
        float denom = fmaxf(sqrtf(n1), EPS_COS) * fmaxf(sqrtf(n2), EPS_COS);
        sred[w] = num / denom;
    }
    __syncthreads();

    if (threadIdx.x == 0) {
        float mx = sred[0];
#pragma unroll
        for (int k = 1; k < NK; ++k) mx = fmaxf(mx, sred[k]);
        float e[NK], sum = 0.f;
#pragma unroll
        for (int k = 0; k < NK; ++k) { e[k] = __expf(sred[k] - mx); sum += e[k]; }
        float invs = 1.f / sum;
        int best = 0; float bv = sred[0];
#pragma unroll
        for (int k = 1; k < NK; ++k) if (sred[k] > bv) { bv = sred[k]; best = k; }
#pragma unroll
        for (int k = 0; k < NK; ++k)
            out[(size_t)NB * ND + b * NK + k] = e[k] * invs;
        bidx = best;
    }
    __syncthreads();

    const float* src = cen + (size_t)(b * NK + bidx) * ND;
    for (int idx = threadIdx.x; idx < ND; idx += 512)
        out[(size_t)b * ND + idx] = src[idx];
}

extern "C" void kernel_launch(void* const* d_in, const int* in_sizes, int n_in,
                              void* d_out, int out_size, void* d_ws, size_t ws_size,
                              hipStream_t stream) {
    // d_in[0]=center_pos, d_in[1]=query_token_ids: unused (log-weight constant)
    const float* cen = (const float*)d_in[2];   // [B,K,d]
    const float* ctx = (const float*)d_in[3];   // [B,C,S,d]
    float* out = (float*)d_out;                 // pooled [B,d] then q [B,K]

    float* part = (float*)d_ws;                 // [B][K][NCG][ND] = 9.8 MB

    k_vam<<<dim3(NB * NCG), dim3(256), 0, stream>>>(ctx, cen, part);
    k_fin2<<<dim3(NB), dim3(512), 0, stream>>>(part, cen, out);
}

// Round 5
// 268.942 us; speedup vs baseline: 1.0055x; 1.0055x over previous
//
#include <hip/hip_runtime.h>

#define NB 32
#define NC 511      // T-1 context positions
#define NK 8        // senses (center)
#define NS 8        // senses (context)
#define ND 300      // embedding dim
#define ND4 75      // float4 per row
#define NCG 32      // c-groups per b (16 c's per block)
#define GPB 4       // sub-groups of 4 c's per block
#define EPS_COS 1e-8f

// Math notes (verified R1-R6, absmax 0.0):
//  - positional log-weight is constant => center_pos/query_token_ids unused.
//  - cosine(cen,m) scale-invariant => accumulate unnormalized m~ = sum_c e^a v.
//  - R10 post-mortem: timed window = ~184us fixed ws-poison fills (2x ~92us,
//    613200KB each, harness re-poison; untouchable) + our kernels.
//  - R11 (238.7 total, best): LDS-fused k_vam at 3.1 TB/s, 512 blocks = 2/CU.
//  - R12 post-mortem (270.4, WORSE): bundled reg-prefetch + raw barriers +
//    grid x2. Prefetch held 64 extra VGPRs live through phase 2 under the
//    128-cap -> spill; raw barriers defeated compiler scheduling. Reverted.
//  - R13: R11 body VERBATIM, one change: NCG 16->32 (1024 blocks = 4/CU).
//    4 independent blocks/CU let inter-block TLP bridge the per-group
//    barrier-drain bubbles without any register-pressure change.

typedef float nfloat4 __attribute__((ext_vector_type(4)));

__device__ __forceinline__ void n4add(nfloat4& a, const nfloat4& b) { a += b; }

// ---------------------------------------------------------------------------
// K1: block = (b, cg) owns 16 consecutive c's, processed as 4 groups of 4
// (wave w -> c = base+w). Per group: batched NT loads -> tree mean -> v tile
// in LDS; 8 dots vs cen; distributed butterfly; ea[0..7] -> LDS; barrier;
// per-d scalar m~ accumulation over the 4 c's; barrier. After 4 groups, one
// coalesced part write. Reads ctx once (157 MB) — the BW-critical pass.
// ---------------------------------------------------------------------------
__global__ __launch_bounds__(256, 4) void k_vam(const float* __restrict__ ctx,
                                                const float* __restrict__ cen,
                                                float* __restrict__ part) {
    const int b    = blockIdx.x >> 5;        // 32 cgroups per b
    const int cg   = blockIdx.x & 31;
    const int w    = threadIdx.x >> 6;       // 4 waves
    const int lane = threadIdx.x & 63;
    const int t    = threadIdx.x;
    const int i0 = lane;
    const int i1 = lane + 64;
    const bool has1  = (i1 < ND4);           // lanes 0..10 own a second float4
    const bool hasd1 = (t < ND - 256);       // threads 0..43 own d = 256+t

    __shared__ float vl[4][ND4 * 4 + 4];     // v tile, padded rows (16B-aligned)
    __shared__ float al[4][NK];              // ea tile

    const nfloat4* cen4 = (const nfloat4*)cen + (size_t)b * NK * ND4;

    float acc0[NK] = {};                     // m~ partial at d = t
    float acc1[NK] = {};                     // m~ partial at d = 256+t (t<44)

    const int cbase0 = cg * (GPB * 4);

    for (int g = 0; g < GPB; ++g) {
        const int cbase = cbase0 + g * 4;
        const int cn = min(4, NC - cbase);   // 3 only for (cg=31, g=3)
        const int c = cbase + w;

        if (c < NC) {                        // wave-uniform
            const nfloat4* ctx4 =
                (const nfloat4*)ctx + (size_t)(b * NC + c) * NS * ND4;

            // ---- batched NT loads: 8 unmasked + one exec-toggle block of 8 ----
            nfloat4 X[NS];
#pragma unroll
            for (int s = 0; s < NS; ++s)
                X[s] = __builtin_nontemporal_load(&ctx4[s * ND4 + i0]);
            nfloat4 Y[NS] = {};              // stays 0 for lanes >= 11
            if (has1) {
#pragma unroll
                for (int s = 0; s < NS; ++s)
                    Y[s] = __builtin_nontemporal_load(&ctx4[s * ND4 + i1]);
            }

            // ---- tree mean over senses ----
            n4add(X[0], X[1]); n4add(X[2], X[3]); n4add(X[4], X[5]); n4add(X[6], X[7]);
            n4add(X[0], X[2]); n4add(X[4], X[6]);
            n4add(X[0], X[4]);
            n4add(Y[0], Y[1]); n4add(Y[2], Y[3]); n4add(Y[4], Y[5]); n4add(Y[6], Y[7]);
            n4add(Y[0], Y[2]); n4add(Y[4], Y[6]);
            n4add(Y[0], Y[4]);
            const float inv = 0.125f;        // 1/S
            nfloat4 s0 = X[0] * inv;
            nfloat4 s1 = Y[0] * inv;         // zero beyond lane 10

            // ---- v -> LDS tile ----
            ((nfloat4*)vl[w])[i0] = s0;
            if (has1) ((nfloat4*)vl[w])[i1] = s1;

            // ---- 8 dots vs cen (L1-resident; reloaded per group, see clobber) ----
            float pk[NK];
#pragma unroll
            for (int k = 0; k < NK; ++k) {
                nfloat4 ca = cen4[k * ND4 + i0];
                float p = ca.x * s0.x + ca.y * s0.y + ca.z * s0.z + ca.w * s0.w;
                if (has1) {
                    nfloat4 cb = cen4[k * ND4 + i1];
                    p += cb.x * s1.x + cb.y * s1.y + cb.z * s1.z + cb.w * s1.w;
                }
                pk[k] = p;
            }

            // ---- distributed exchange-butterfly: lane l -> total for k=l&7 ----
            const bool b0 = (lane & 1) != 0;
            float r[4];
#pragma unroll
            for (int j = 0; j < 4; ++j) {
                float keep = b0 ? pk[2 * j + 1] : pk[2 * j];
                float send = b0 ? pk[2 * j]     : pk[2 * j + 1];
                r[j] = keep + __shfl_xor(send, 1);
            }
            const bool b1 = (lane & 2) != 0;
            float q0, q1;
            { float keep = b1 ? r[1] : r[0]; float send = b1 ? r[0] : r[1];
              q0 = keep + __shfl_xor(send, 2); }
            { float keep = b1 ? r[3] : r[2]; float send = b1 ? r[2] : r[3];
              q1 = keep + __shfl_xor(send, 2); }
            const bool b2 = (lane & 4) != 0;
            float u;
            { float keep = b2 ? q1 : q0; float send = b2 ? q0 : q1;
              u = keep + __shfl_xor(send, 4); }
            u += __shfl_xor(u, 8);
            u += __shfl_xor(u, 16);
            u += __shfl_xor(u, 32);

            if (lane < NK) {
                const float scale = 0.057735026919f; // 1/sqrt(300)
                al[w][lane] = __expf(u * scale);
            }
        }
        __syncthreads();

        // ---- phase 2: per-d scalar m~ accumulation (c ascending) ----
        for (int cc = 0; cc < cn; ++cc) {
            float vv0 = vl[cc][t];
#pragma unroll
            for (int k = 0; k < NK; ++k) acc0[k] += al[cc][k] * vv0;
        }
        if (hasd1) {
            for (int cc = 0; cc < cn; ++cc) {
                float vv1 = vl[cc][256 + t];
#pragma unroll
                for (int k = 0; k < NK; ++k) acc1[k] += al[cc][k] * vv1;
            }
        }
        __syncthreads();
        // stop cen/ctx address + cen-fragment hoisting across groups (keeps
        // VGPR pressure at the single-group level; cen stays L1-warm anyway)
        asm volatile("" ::: "memory");
    }

    // ---- one coalesced part write per k ----
#pragma unroll
    for (int k = 0; k < NK; ++k) {
        float* pp = part + (((size_t)(b * NK + k)) * NCG + cg) * ND;
        pp[t] = acc0[k];
        if (hasd1) pp[256 + t] = acc1[k];
    }
}

// ---------------------------------------------------------------------------
// K2: per b — wave w owns k=w: sum the 32 m~ chunk-partials along d (contiguous
// [NCG][ND] panel per (b,k)), cosine vs cen row, then softmax/argmax/pooled.
// ---------------------------------------------------------------------------
__global__ __launch_bounds__(512) void k_fin2(const float* __restrict__ part,
                                              const float* __restrict__ cen,
                                              float* __restrict__ out) {
    const int b    = blockIdx.x;
    const int w    = threadIdx.x >> 6;       // = k
    const int lane = threadIdx.x & 63;
    __shared__ float sred[NK];
    __shared__ int bidx;

    const float* pp = part + ((size_t)b * NK + w) * NCG * ND;
    const float* cp = cen + (size_t)(b * NK + w) * ND;
    float num = 0.f, n1 = 0.f, n2 = 0.f;
    for (int d = lane; d < ND; d += 64) {
        float mval = 0.f;
#pragma unroll
        for (int cg = 0; cg < NCG; ++cg) mval += pp[cg * ND + d];
        float cv = cp[d];
        num += cv * mval; n1 += cv * cv; n2 += mval * mval;
    }
#pragma unroll
    for (int off = 32; off; off >>= 1) {
        num += __shfl_down(num, off);
        n1  += __shfl_down(n1, off);
        n2  += __shfl_down(n2, off);
    }
    if (lane == 0) {
        float denom = fmaxf(sqrtf(n1), EPS_COS) * fmaxf(sqrtf(n2), EPS_COS);
        sred[w] = num / denom;
    }
    __syncthreads();

    if (threadIdx.x == 0) {
        float mx = sred[0];
#pragma unroll
        for (int k = 1; k < NK; ++k) mx = fmaxf(mx, sred[k]);
        float e[NK], sum = 0.f;
#pragma unroll
        for (int k = 0; k < NK; ++k) { e[k] = __expf(sred[k] - mx); sum += e[k]; }
        float invs = 1.f / sum;
        int best = 0; float bv = sred[0];
#pragma unroll
        for (int k = 1; k < NK; ++k) if (sred[k] > bv) { bv = sred[k]; best = k; }
#pragma unroll
        for (int k = 0; k < NK; ++k)
            out[(size_t)NB * ND + b * NK + k] = e[k] * invs;
        bidx = best;
    }
    __syncthreads();

    const float* src = cen + (size_t)(b * NK + bidx) * ND;
    for (int idx = threadIdx.x; idx < ND; idx += 512)
        out[(size_t)b * ND + idx] = src[idx];
}

extern "C" void kernel_launch(void* const* d_in, const int* in_sizes, int n_in,
                              void* d_out, int out_size, void* d_ws, size_t ws_size,
                              hipStream_t stream) {
    // d_in[0]=center_pos, d_in[1]=query_token_ids: unused (log-weight constant)
    const float* cen = (const float*)d_in[2];   // [B,K,d]
    const float* ctx = (const float*)d_in[3];   // [B,C,S,d]
    float* out = (float*)d_out;                 // pooled [B,d] then q [B,K]

    float* part = (float*)d_ws;                 // [B][K][NCG][ND] = 9.8 MB

    k_vam<<<dim3(NB * NCG), dim3(256), 0, stream>>>(ctx, cen, part);
    k_fin2<<<dim3(NB), dim3(512), 0, stream>>>(part, cen, out);
}

// Round 6
// 233.762 us; speedup vs baseline: 1.1569x; 1.1505x over previous
//
#include <hip/hip_runtime.h>

#define NB 32
#define NC 511      // T-1 context positions
#define NK 8        // senses (center)
#define NS 8        // senses (context)
#define ND 300      // embedding dim
#define ND4 75      // float4 per row
#define NCG 16      // c-groups per b (32 c's per block) -- 512 blocks total
#define GPB 8       // sub-groups of 4 c's per block
#define EPS_COS 1e-8f

// Math notes (verified R1-R6, absmax 0.0):
//  - positional log-weight is constant => center_pos/query_token_ids unused.
//  - cosine(cen,m) scale-invariant => accumulate unnormalized m~ = sum_c e^a v.
//  - R10 post-mortem: timed window = ~184us fixed ws-poison fills (2x ~92us),
//    untouchable; our kernels are the only lever.
//  - R12/R13 A/B decomposition: NCG 16->32 (1024 blocks) = +30us BOTH rounds
//    (DRAM stream-count effect, not occupancy); prefetch+raw-barriers ~neutral.
//    => KEEP 512 BLOCKS. R11 (238.7) = best.
//  - R14: R11 grid/shape + LDS double-buffer -> ONE barrier per group; next
//    group's NT loads issue right after the barrier, BEFORE phase 2, so the
//    ~900cy HBM latency hides under phase2's LDS+FMA work. Safety: phase2(g)
//    reads buf[g&1], writes go to buf[(g+1)&1]; top-of-iter barrier guarantees
//    all waves left phase2(g-1) before its buffer is overwritten. al reads
//    vectorized to 2x ds_read_b128. launch_bounds(256,2): grid caps residency
//    at 2 blocks/CU anyway; higher VGPR cap removes spill risk.

typedef float nfloat4 __attribute__((ext_vector_type(4)));

__device__ __forceinline__ void n4add(nfloat4& a, const nfloat4& b) { a += b; }

// ---------------------------------------------------------------------------
// K1: block = (b, cg) owns 32 consecutive c's as 8 groups of 4 (wave w ->
// c = base+w). Software-pipelined: prologue computes group 0 into buf0; each
// iteration: barrier; issue NT loads for g+1; phase2 accumulate from buf[g&1];
// compute v/ea for g+1 into buf[(g+1)&1]. One coalesced part write at end.
// ---------------------------------------------------------------------------
__global__ __launch_bounds__(256, 2) void k_vam(const float* __restrict__ ctx,
                                                const float* __restrict__ cen,
                                                float* __restrict__ part) {
    const int b    = blockIdx.x >> 4;        // 16 cgroups per b
    const int cg   = blockIdx.x & 15;
    const int w    = threadIdx.x >> 6;       // 4 waves
    const int lane = threadIdx.x & 63;
    const int t    = threadIdx.x;
    const int i0 = lane;
    const int i1 = lane + 64;
    const bool has1  = (i1 < ND4);           // lanes 0..10 own a second float4
    const bool hasd1 = (t < ND - 256);       // threads 0..43 own d = 256+t

    __shared__ float vl[2][4][ND4 * 4 + 4];  // v tiles, padded rows
    __shared__ float al[2][4][NK];           // ea tiles (rows 32B-aligned)

    const nfloat4* cen4 = (const nfloat4*)cen + (size_t)b * NK * ND4;

    float acc0[NK] = {};                     // m~ partial at d = t
    float acc1[NK] = {};                     // m~ partial at d = 256+t (t<44)

    const int cbase0 = cg * (GPB * 4);

    nfloat4 X[NS];
    nfloat4 Y[NS] = {};                      // lanes >= 11 stay zero forever

    // ---------------- prologue: load + compute group 0 -> buf 0 ------------
    {
        const int c = cbase0 + w;            // always < NC (max 483)
        const nfloat4* ctx4 =
            (const nfloat4*)ctx + (size_t)(b * NC + c) * NS * ND4;
#pragma unroll
        for (int s = 0; s < NS; ++s)
            X[s] = __builtin_nontemporal_load(&ctx4[s * ND4 + i0]);
        if (has1) {
#pragma unroll
            for (int s = 0; s < NS; ++s)
                Y[s] = __builtin_nontemporal_load(&ctx4[s * ND4 + i1]);
        }
        n4add(X[0], X[1]); n4add(X[2], X[3]); n4add(X[4], X[5]); n4add(X[6], X[7]);
        n4add(X[0], X[2]); n4add(X[4], X[6]);
        n4add(X[0], X[4]);
        n4add(Y[0], Y[1]); n4add(Y[2], Y[3]); n4add(Y[4], Y[5]); n4add(Y[6], Y[7]);
        n4add(Y[0], Y[2]); n4add(Y[4], Y[6]);
        n4add(Y[0], Y[4]);
        const float inv = 0.125f;
        nfloat4 s0 = X[0] * inv;
        nfloat4 s1 = Y[0] * inv;

        ((nfloat4*)vl[0][w])[i0] = s0;
        if (has1) ((nfloat4*)vl[0][w])[i1] = s1;

        float pk[NK];
#pragma unroll
        for (int k = 0; k < NK; ++k) {
            nfloat4 ca = cen4[k * ND4 + i0];
            float p = ca.x * s0.x + ca.y * s0.y + ca.z * s0.z + ca.w * s0.w;
            if (has1) {
                nfloat4 cb = cen4[k * ND4 + i1];
                p += cb.x * s1.x + cb.y * s1.y + cb.z * s1.z + cb.w * s1.w;
            }
            pk[k] = p;
        }
        const bool b0 = (lane & 1) != 0;
        float r[4];
#pragma unroll
        for (int j = 0; j < 4; ++j) {
            float keep = b0 ? pk[2 * j + 1] : pk[2 * j];
            float send = b0 ? pk[2 * j]     : pk[2 * j + 1];
            r[j] = keep + __shfl_xor(send, 1);
        }
        const bool b1 = (lane & 2) != 0;
        float q0, q1;
        { float keep = b1 ? r[1] : r[0]; float send = b1 ? r[0] : r[1];
          q0 = keep + __shfl_xor(send, 2); }
        { float keep = b1 ? r[3] : r[2]; float send = b1 ? r[2] : r[3];
          q1 = keep + __shfl_xor(send, 2); }
        const bool b2 = (lane & 4) != 0;
        float u;
        { float keep = b2 ? q1 : q0; float send = b2 ? q0 : q1;
          u = keep + __shfl_xor(send, 4); }
        u += __shfl_xor(u, 8);
        u += __shfl_xor(u, 16);
        u += __shfl_xor(u, 32);
        if (lane < NK) {
            const float scale = 0.057735026919f; // 1/sqrt(300)
            al[0][w][lane] = __expf(u * scale);
        }
    }

    // ---------------- pipelined main loop ----------------------------------
    for (int g = 0; g < GPB; ++g) {
        __syncthreads();                     // buf[g&1] ready; buf[(g+1)&1] free

        const int buf = g & 1;
        const int nbf = buf ^ 1;
        const int cn  = min(4, NC - (cbase0 + g * 4));  // 3 only at cg=15,g=7

        // ---- issue next group's NT loads (in flight during phase 2) ----
        const bool cvn = (g + 1 < GPB) && (cbase0 + (g + 1) * 4 + w < NC);
        if (cvn) {
            const int cnx = cbase0 + (g + 1) * 4 + w;
            const nfloat4* ctx4 =
                (const nfloat4*)ctx + (size_t)(b * NC + cnx) * NS * ND4;
#pragma unroll
            for (int s = 0; s < NS; ++s)
                X[s] = __builtin_nontemporal_load(&ctx4[s * ND4 + i0]);
            if (has1) {
#pragma unroll
                for (int s = 0; s < NS; ++s)
                    Y[s] = __builtin_nontemporal_load(&ctx4[s * ND4 + i1]);
            }
        }

        // ---- phase 2: per-d scalar m~ accumulation from buf (c ascending) ----
        for (int cc = 0; cc < cn; ++cc) {
            nfloat4 a0 = ((const nfloat4*)al[buf][cc])[0];
            nfloat4 a1 = ((const nfloat4*)al[buf][cc])[1];
            float vv0 = vl[buf][cc][t];
            acc0[0] += a0.x * vv0; acc0[1] += a0.y * vv0;
            acc0[2] += a0.z * vv0; acc0[3] += a0.w * vv0;
            acc0[4] += a1.x * vv0; acc0[5] += a1.y * vv0;
            acc0[6] += a1.z * vv0; acc0[7] += a1.w * vv0;
            if (hasd1) {
                float vv1 = vl[buf][cc][256 + t];
                acc1[0] += a0.x * vv1; acc1[1] += a0.y * vv1;
                acc1[2] += a0.z * vv1; acc1[3] += a0.w * vv1;
                acc1[4] += a1.x * vv1; acc1[5] += a1.y * vv1;
                acc1[6] += a1.z * vv1; acc1[7] += a1.w * vv1;
            }
        }

        // ---- compute v/ea for group g+1 into the other buffer ----
        if (cvn) {
            n4add(X[0], X[1]); n4add(X[2], X[3]); n4add(X[4], X[5]); n4add(X[6], X[7]);
            n4add(X[0], X[2]); n4add(X[4], X[6]);
            n4add(X[0], X[4]);
            n4add(Y[0], Y[1]); n4add(Y[2], Y[3]); n4add(Y[4], Y[5]); n4add(Y[6], Y[7]);
            n4add(Y[0], Y[2]); n4add(Y[4], Y[6]);
            n4add(Y[0], Y[4]);
            const float inv = 0.125f;
            nfloat4 s0 = X[0] * inv;
            nfloat4 s1 = Y[0] * inv;

            ((nfloat4*)vl[nbf][w])[i0] = s0;
            if (has1) ((nfloat4*)vl[nbf][w])[i1] = s1;

            float pk[NK];
#pragma unroll
            for (int k = 0; k < NK; ++k) {
                nfloat4 ca = cen4[k * ND4 + i0];
                float p = ca.x * s0.x + ca.y * s0.y + ca.z * s0.z + ca.w * s0.w;
                if (has1) {
                    nfloat4 cb = cen4[k * ND4 + i1];
                    p += cb.x * s1.x + cb.y * s1.y + cb.z * s1.z + cb.w * s1.w;
                }
                pk[k] = p;
            }
            const bool b0 = (lane & 1) != 0;
            float r[4];
#pragma unroll
            for (int j = 0; j < 4; ++j) {
                float keep = b0 ? pk[2 * j + 1] : pk[2 * j];
                float send = b0 ? pk[2 * j]     : pk[2 * j + 1];
                r[j] = keep + __shfl_xor(send, 1);
            }
            const bool b1 = (lane & 2) != 0;
            float q0, q1;
            { float keep = b1 ? r[1] : r[0]; float send = b1 ? r[0] : r[1];
              q0 = keep + __shfl_xor(send, 2); }
            { float keep = b1 ? r[3] : r[2]; float send = b1 ? r[2] : r[3];
              q1 = keep + __shfl_xor(send, 2); }
            const bool b2 = (lane & 4) != 0;
            float u;
            { float keep = b2 ? q1 : q0; float send = b2 ? q0 : q1;
              u = keep + __shfl_xor(send, 4); }
            u += __shfl_xor(u, 8);
            u += __shfl_xor(u, 16);
            u += __shfl_xor(u, 32);
            if (lane < NK) {
                const float scale = 0.057735026919f; // 1/sqrt(300)
                al[nbf][w][lane] = __expf(u * scale);
            }
        }
        // keep cen fragments from being hoisted/kept across iterations
        asm volatile("" ::: "memory");
    }

    // ---- one coalesced part write per k ----
#pragma unroll
    for (int k = 0; k < NK; ++k) {
        float* pp = part + (((size_t)(b * NK + k)) * NCG + cg) * ND;
        pp[t] = acc0[k];
        if (hasd1) pp[256 + t] = acc1[k];
    }
}

// ---------------------------------------------------------------------------
// K2: per b — wave w owns k=w: sum the 16 m~ chunk-partials along d (contiguous
// [NCG][ND] panel per (b,k)), cosine vs cen row, then softmax/argmax/pooled.
// ---------------------------------------------------------------------------
__global__ __launch_bounds__(512) void k_fin2(const float* __restrict__ part,
                                              const float* __restrict__ cen,
                                              float* __restrict__ out) {
    const int b    = blockIdx.x;
    const int w    = threadIdx.x >> 6;       // = k
    const int lane = threadIdx.x & 63;
    __shared__ float sred[NK];
    __shared__ int bidx;

    const float* pp = part + ((size_t)b * NK + w) * NCG * ND;
    const float* cp = cen + (size_t)(b * NK + w) * ND;
    float num = 0.f, n1 = 0.f, n2 = 0.f;
    for (int d = lane; d < ND; d += 64) {
        float mval = 0.f;
#pragma unroll
        for (int cg = 0; cg < NCG; ++cg) mval += pp[cg * ND + d];
        float cv = cp[d];
        num += cv * mval; n1 += cv * cv; n2 += mval * mval;
    }
#pragma unroll
    for (int off = 32; off; off >>= 1) {
        num += __shfl_down(num, off);
        n1  += __shfl_down(n1, off);
        n2  += __shfl_down(n2, off);
    }
    if (lane == 0) {
        float denom = fmaxf(sqrtf(n1), EPS_COS) * fmaxf(sqrtf(n2), EPS_COS);
        sred[w] = num / denom;
    }
    __syncthreads();

    if (threadIdx.x == 0) {
        float mx = sred[0];
#pragma unroll
        for (int k = 1; k < NK; ++k) mx = fmaxf(mx, sred[k]);
        float e[NK], sum = 0.f;
#pragma unroll
        for (int k = 0; k < NK; ++k) { e[k] = __expf(sred[k] - mx); sum += e[k]; }
        float invs = 1.f / sum;
        int best = 0; float bv = sred[0];
#pragma unroll
        for (int k = 1; k < NK; ++k) if (sred[k] > bv) { bv = sred[k]; best = k; }
#pragma unroll
        for (int k = 0; k < NK; ++k)
            out[(size_t)NB * ND + b * NK + k] = e[k] * invs;
        bidx = best;
    }
    __syncthreads();

    const float* src = cen + (size_t)(b * NK + bidx) * ND;
    for (int idx = threadIdx.x; idx < ND; idx += 512)
        out[(size_t)b * ND + idx] = src[idx];
}

extern "C" void kernel_launch(void* const* d_in, const int* in_sizes, int n_in,
                              void* d_out, int out_size, void* d_ws, size_t ws_size,
                              hipStream_t stream) {
    // d_in[0]=center_pos, d_in[1]=query_token_ids: unused (log-weight constant)
    const float* cen = (const float*)d_in[2];   // [B,K,d]
    const float* ctx = (const float*)d_in[3];   // [B,C,S,d]
    float* out = (float*)d_out;                 // pooled [B,d] then q [B,K]

    float* part = (float*)d_ws;                 // [B][K][NCG][ND] = 4.9 MB

    k_vam<<<dim3(NB * NCG), dim3(256), 0, stream>>>(ctx, cen, part);
    k_fin2<<<dim3(NB), dim3(512), 0, stream>>>(part, cen, out);
}